// Round 1
// baseline (1247.748 us; speedup 1.0000x reference)
//
#include <hip/hip_runtime.h>

#define H 128
#define THREE_H 384
#define BR 4

__device__ __forceinline__ float fsig(float x) {
  return 1.0f / (1.0f + __expf(-x));
}
__device__ __forceinline__ float ftanh(float x) {
  float ax = fabsf(x);
  float e = __expf(-2.0f * ax);           // in (0,1], no overflow
  float t = (1.0f - e) / (1.0f + e);
  return x < 0.0f ? -t : t;
}

// ---------------- Leaf kernel: h,c = apply(x@W_iou + b, 0) ----------------
#define LNR 32   // nodes per block
#define LRP 16   // rows per thread (LNR/2)

__global__ __launch_bounds__(256)
void leaf_kernel(const float* __restrict__ x,
                 const float* __restrict__ W_iou,
                 const float* __restrict__ b_iou,
                 float* __restrict__ h_out,
                 float* __restrict__ c_out,
                 int leaf_start)
{
  __shared__ float xs[LNR][H];            // 16 KB
  const int t = threadIdx.x;
  const int node0 = blockIdx.x * LNR;

  // stage x tile (coalesced float4)
  {
    const float4* xgv = reinterpret_cast<const float4*>(x + (size_t)(leaf_start + node0) * H);
    float4* xsv = reinterpret_cast<float4*>(&xs[0][0]);
    #pragma unroll
    for (int i = 0; i < (LNR * H / 4) / 256; i++)
      xsv[t + i * 256] = xgv[t + i * 256];
  }
  __syncthreads();

  const int ch = t & (H - 1);
  const int g  = t >> 7;                  // 0 or 1 -> node half

  float ai[LRP], ao[LRP], au[LRP];
  {
    float bi = b_iou[ch], bo = b_iou[ch + H], bu = b_iou[ch + 2 * H];
    #pragma unroll
    for (int r = 0; r < LRP; r++) { ai[r] = bi; ao[r] = bo; au[r] = bu; }
  }
  const float* wp = W_iou + ch;
  #pragma unroll 4
  for (int k = 0; k < H; k++) {
    float w0 = wp[k * THREE_H];
    float w1 = wp[k * THREE_H + H];
    float w2 = wp[k * THREE_H + 2 * H];
    #pragma unroll
    for (int r = 0; r < LRP; r++) {
      float xk = xs[g * LRP + r][k];      // wave-uniform broadcast
      ai[r] = fmaf(xk, w0, ai[r]);
      ao[r] = fmaf(xk, w1, ao[r]);
      au[r] = fmaf(xk, w2, au[r]);
    }
  }
  #pragma unroll
  for (int r = 0; r < LRP; r++) {
    float c = fsig(ai[r]) * ftanh(au[r]);
    float h = fsig(ao[r]) * ftanh(c);
    size_t node = (size_t)(leaf_start + node0 + g * LRP + r);
    h_out[node * H + ch] = h;
    c_out[node * H + ch] = c;
  }
}

// ---------------- Internal-level kernel ----------------
#define INR 16   // nodes per block
#define IRP 8    // rows per thread (INR/2)

__global__ __launch_bounds__(256)
void internal_kernel(const float* __restrict__ x,
                     const float* __restrict__ W_iou,
                     const float* __restrict__ b_iou,
                     const float* __restrict__ U_iou,
                     const float* __restrict__ W_f,
                     const float* __restrict__ U_f,
                     const float* __restrict__ b_f,
                     float* __restrict__ h_out,
                     float* __restrict__ c_out,
                     int lvl_start, int child_start, int n_lvl)
{
  __shared__ float xs[INR][H];            // 8 KB
  __shared__ float hs[INR * BR][H];       // 32 KB (children h, contiguous rows)
  __shared__ float ht[INR][H];            // 8 KB  (h_tilda)
  const int t = threadIdx.x;
  const int node0 = blockIdx.x * INR;
  const int nrows = min(INR, n_lvl - node0);

  // stage x rows
  {
    const float4* xgv = reinterpret_cast<const float4*>(x + (size_t)(lvl_start + node0) * H);
    float4* xsv = reinterpret_cast<float4*>(&xs[0][0]);
    int total = nrows * (H / 4);
    for (int i = t; i < total; i += 256) xsv[i] = xgv[i];
  }
  // stage children h rows (children of the tile are contiguous)
  {
    const float4* hgv = reinterpret_cast<const float4*>(h_out + (size_t)(child_start + node0 * BR) * H);
    float4* hsv = reinterpret_cast<float4*>(&hs[0][0]);
    int total = nrows * BR * (H / 4);
    for (int i = t; i < total; i += 256) hsv[i] = hgv[i];
  }
  __syncthreads();

  const int ch = t & (H - 1);
  const int g  = t >> 7;

  float fx[IRP], ai[IRP], ao[IRP], au[IRP];
  {
    float bi = b_iou[ch], bo = b_iou[ch + H], bu = b_iou[ch + 2 * H], bf = b_f[ch];
    #pragma unroll
    for (int r = 0; r < IRP; r++) { fx[r] = bf; ai[r] = bi; ao[r] = bo; au[r] = bu; }
  }

  // phase 1: x @ [W_f | W_iou]
  {
    const float* wfp = W_f + ch;
    const float* wip = W_iou + ch;
    #pragma unroll 4
    for (int k = 0; k < H; k++) {
      float wf = wfp[k * H];
      float w0 = wip[k * THREE_H];
      float w1 = wip[k * THREE_H + H];
      float w2 = wip[k * THREE_H + 2 * H];
      #pragma unroll
      for (int r = 0; r < IRP; r++) {
        float xk = xs[g * IRP + r][k];
        fx[r] = fmaf(xk, wf, fx[r]);
        ai[r] = fmaf(xk, w0, ai[r]);
        ao[r] = fmaf(xk, w1, ao[r]);
        au[r] = fmaf(xk, w2, au[r]);
      }
    }
  }

  // h_tilda = sum of children h (per channel), stash to LDS for phase 3
  #pragma unroll
  for (int r = 0; r < IRP; r++) {
    int row = g * IRP + r;
    float s = hs[row * BR + 0][ch] + hs[row * BR + 1][ch]
            + hs[row * BR + 2][ch] + hs[row * BR + 3][ch];
    ht[row][ch] = s;
  }
  __syncthreads();

  // phase 2: f gates (children_h @ U_f + node_f) and csum = sum f*c_child
  float z[BR][IRP];
  #pragma unroll
  for (int kc = 0; kc < BR; kc++)
    #pragma unroll
    for (int r = 0; r < IRP; r++) z[kc][r] = fx[r];
  {
    const float* ufp = U_f + ch;
    #pragma unroll 4
    for (int m = 0; m < H; m++) {
      float uf = ufp[m * H];
      #pragma unroll
      for (int kc = 0; kc < BR; kc++)
        #pragma unroll
        for (int r = 0; r < IRP; r++)
          z[kc][r] = fmaf(hs[(g * IRP + r) * BR + kc][m], uf, z[kc][r]);
    }
  }
  float csum[IRP];
  #pragma unroll
  for (int r = 0; r < IRP; r++) csum[r] = 0.0f;
  #pragma unroll
  for (int kc = 0; kc < BR; kc++) {
    #pragma unroll
    for (int r = 0; r < IRP; r++) {
      size_t childnode = (size_t)child_start + (size_t)(node0 + g * IRP + r) * BR + kc;
      float f = fsig(z[kc][r]);
      csum[r] = fmaf(f, c_out[childnode * H + ch], csum[r]);
    }
  }

  // phase 3: iou += h_tilda @ U_iou
  {
    const float* uip = U_iou + ch;
    #pragma unroll 4
    for (int m = 0; m < H; m++) {
      float w0 = uip[m * THREE_H];
      float w1 = uip[m * THREE_H + H];
      float w2 = uip[m * THREE_H + 2 * H];
      #pragma unroll
      for (int r = 0; r < IRP; r++) {
        float hm = ht[g * IRP + r][m];
        ai[r] = fmaf(hm, w0, ai[r]);
        ao[r] = fmaf(hm, w1, ao[r]);
        au[r] = fmaf(hm, w2, au[r]);
      }
    }
  }

  // finalize
  #pragma unroll
  for (int r = 0; r < IRP; r++) {
    int row = g * IRP + r;
    if (row < nrows) {
      float c = fsig(ai[r]) * ftanh(au[r]) + csum[r];
      float h = fsig(ao[r]) * ftanh(c);
      size_t node = (size_t)(lvl_start + node0 + row);
      h_out[node * H + ch] = h;
      c_out[node * H + ch] = c;
    }
  }
}

extern "C" void kernel_launch(void* const* d_in, const int* in_sizes, int n_in,
                              void* d_out, int out_size, void* d_ws, size_t ws_size,
                              hipStream_t stream)
{
  const float* x     = (const float*)d_in[0];
  const float* W_iou = (const float*)d_in[1];
  const float* U_iou = (const float*)d_in[2];
  const float* b_iou = (const float*)d_in[3];
  const float* W_f   = (const float*)d_in[4];
  const float* U_f   = (const float*)d_in[5];
  const float* b_f   = (const float*)d_in[6];
  // depth=10, branching=4 (reference constants)
  const int N = 349525;

  float* h_out = (float*)d_out;
  float* c_out = h_out + (size_t)N * H;

  int off[11];
  off[0] = 0;
  for (int l = 1; l <= 10; l++) off[l] = off[l - 1] * 4 + 1;   // (4^l - 1)/3

  // leaves: level 9 (262144 nodes)
  {
    int leaf_start = off[9];
    int n_leaf = off[10] - off[9];
    leaf_kernel<<<n_leaf / LNR, 256, 0, stream>>>(x, W_iou, b_iou, h_out, c_out, leaf_start);
  }
  // internal levels bottom-up
  for (int l = 8; l >= 0; l--) {
    int s = off[l], e = off[l + 1];
    int n = e - s;
    int grid = (n + INR - 1) / INR;
    internal_kernel<<<grid, 256, 0, stream>>>(x, W_iou, b_iou, U_iou, W_f, U_f, b_f,
                                              h_out, c_out, s, e, n);
  }
}

// Round 2
// 1182.176 us; speedup vs baseline: 1.0555x; 1.0555x over previous
//
#include <hip/hip_runtime.h>

#define H 128
#define BR 4

typedef __bf16 bf16x8 __attribute__((ext_vector_type(8)));
typedef float f32x4 __attribute__((ext_vector_type(4)));

__device__ __forceinline__ float fsig(float x) { return 1.0f / (1.0f + __expf(-x)); }
__device__ __forceinline__ float ftanh(float x) {
  float ax = fabsf(x), e = __expf(-2.0f * ax);
  float t = (1.0f - e) / (1.0f + e);
  return x < 0.0f ? -t : t;
}
__device__ __forceinline__ unsigned short f2bf(float f) {
  union { float f; unsigned u; } v; v.f = f;
  unsigned r = v.u + 0x7FFF + ((v.u >> 16) & 1);   // RNE
  return (unsigned short)(r >> 16);
}
__device__ __forceinline__ uint2 pack4(float a, float b, float c, float d) {
  uint2 r;
  r.x = (unsigned)f2bf(a) | ((unsigned)f2bf(b) << 16);
  r.y = (unsigned)f2bf(c) | ((unsigned)f2bf(d) << 16);
  return r;
}
// XOR swizzle: conflict-free ds_read_b128 on row-major bf16 tiles (T2)
__device__ __forceinline__ unsigned swz(unsigned row, unsigned colByte, unsigned rowBytes) {
  return (row * rowBytes + colByte) ^ ((row & 7) << 4);
}

// ============ F kernel: f = sig([h_c|x_p]@[U_f;W_f] + b_f); csum -> c[parent] ============
__global__ __launch_bounds__(256)
void fgate_kernel(const float* __restrict__ x, const float* __restrict__ U_f,
                  const float* __restrict__ W_f, const float* __restrict__ b_f,
                  const float* __restrict__ h_glob, float* __restrict__ c_glob,
                  int pstart, int cstart)
{
  __shared__ __align__(16) char As[128 * 512];  // [128 child rows][K=256] bf16
  __shared__ __align__(16) char Bs[128 * 512];  // BT [128 ch][K=256] bf16
  const int t = threadIdx.x;
  const int bid = blockIdx.x;
  const int c0 = bid * 128;

  // stage A = [h_child | x_parent]
  for (int idx = t; idx < 128 * 64; idx += 256) {
    int r = idx >> 6;
    int k0 = (idx & 63) << 2;
    f32x4 v;
    if (k0 < 128) {
      v = *reinterpret_cast<const f32x4*>(&h_glob[(size_t)(cstart + c0 + r) * H + k0]);
    } else {
      int p = pstart + ((c0 + r) >> 2);
      v = *reinterpret_cast<const f32x4*>(&x[(size_t)p * H + (k0 - 128)]);
    }
    *reinterpret_cast<uint2*>(As + swz(r, k0 * 2, 512)) = pack4(v.x, v.y, v.z, v.w);
  }
  // stage B^T: row n (=ch), k<128 -> U_f[k][n], else W_f[k-128][n]
  for (int idx = t; idx < 128 * 64; idx += 256) {
    int n = idx & 127;
    int k0 = (idx >> 7) << 2;
    float a0, a1, a2, a3;
    if (k0 < 128) {
      a0 = U_f[(k0 + 0) * H + n]; a1 = U_f[(k0 + 1) * H + n];
      a2 = U_f[(k0 + 2) * H + n]; a3 = U_f[(k0 + 3) * H + n];
    } else {
      int kk = k0 - 128;
      a0 = W_f[(kk + 0) * H + n]; a1 = W_f[(kk + 1) * H + n];
      a2 = W_f[(kk + 2) * H + n]; a3 = W_f[(kk + 3) * H + n];
    }
    *reinterpret_cast<uint2*>(Bs + swz(n, k0 * 2, 512)) = pack4(a0, a1, a2, a3);
  }
  __syncthreads();

  const int lane = t & 63, wid = t >> 6;
  const int wr = wid >> 1, wc = wid & 1;     // wave tile 64x64
  const int l15 = lane & 15, l4 = lane >> 4;

  f32x4 acc[4][4] = {};
  #pragma unroll
  for (int ks = 0; ks < 8; ks++) {
    bf16x8 a[4], b[4];
    #pragma unroll
    for (int m = 0; m < 4; m++)
      a[m] = *reinterpret_cast<const bf16x8*>(As + swz(wr * 64 + m * 16 + l15, (ks * 32 + l4 * 8) * 2, 512));
    #pragma unroll
    for (int n = 0; n < 4; n++)
      b[n] = *reinterpret_cast<const bf16x8*>(Bs + swz(wc * 64 + n * 16 + l15, (ks * 32 + l4 * 8) * 2, 512));
    #pragma unroll
    for (int m = 0; m < 4; m++)
      #pragma unroll
      for (int n = 0; n < 4; n++)
        acc[m][n] = __builtin_amdgcn_mfma_f32_16x16x32_bf16(a[m], b[n], acc[m][n], 0, 0, 0);
  }

  // epilogue: 4 regs of a lane = 4 consecutive child rows = one parent
  #pragma unroll
  for (int m = 0; m < 4; m++) {
    int rbase = wr * 64 + m * 16 + l4 * 4;          // multiple of 4
    int p = pstart + bid * 32 + (rbase >> 2);
    #pragma unroll
    for (int n = 0; n < 4; n++) {
      int ch = wc * 64 + n * 16 + l15;
      float bf = b_f[ch];
      float cs = 0.0f;
      #pragma unroll
      for (int r = 0; r < 4; r++) {
        float f = fsig(acc[m][n][r] + bf);
        float cc = c_glob[(size_t)(cstart + c0 + rbase + r) * H + ch];
        cs = fmaf(f, cc, cs);
      }
      c_glob[(size_t)p * H + ch] = cs;   // csum staged; IOU kernel finalizes
    }
  }
}

// ============ IOU kernel (and leaves): [x | h_tilda] @ [W_iou;U_iou], gate-gathered ============
template<int BM, int BK, bool LEAF>
__global__ __launch_bounds__(256)
void iou_kernel(const float* __restrict__ x, const float* __restrict__ W_iou,
                const float* __restrict__ U_iou, const float* __restrict__ b_iou,
                float* __restrict__ h_glob, float* __restrict__ c_glob,
                int pstart, int cstart)
{
  constexpr int RB = BK * 2;
  constexpr int MF = BM / 64;          // row-frags per wave (wave M-tile = BM/4)
  __shared__ __align__(16) char As[BM * RB];    // [BM][BK]
  __shared__ __align__(16) char Bs[192 * RB];   // BT [192][BK]
  const int t = threadIdx.x;
  const int bid = blockIdx.x;
  const int ch0 = blockIdx.y * 64;
  const int p0 = bid * BM;

  // stage A: k<128 -> x ; k>=128 -> h_tilda = sum of 4 children h
  for (int idx = t; idx < BM * (BK / 4); idx += 256) {
    int r = idx / (BK / 4);
    int k0 = (idx % (BK / 4)) * 4;
    uint2 w;
    if (LEAF || k0 < 128) {
      f32x4 v = *reinterpret_cast<const f32x4*>(&x[(size_t)(pstart + p0 + r) * H + k0]);
      w = pack4(v.x, v.y, v.z, v.w);
    } else {
      int cbase = cstart + (p0 + r) * 4;
      f32x4 s = {};
      #pragma unroll
      for (int j = 0; j < 4; j++) {
        f32x4 v = *reinterpret_cast<const f32x4*>(&h_glob[(size_t)(cbase + j) * H + (k0 - 128)]);
        s.x += v.x; s.y += v.y; s.z += v.z; s.w += v.w;
      }
      w = pack4(s.x, s.y, s.z, s.w);
    }
    *reinterpret_cast<uint2*>(As + swz(r, k0 * 2, RB)) = w;
  }
  // stage B^T: row n in [0,192): gate g=n>>6, col = g*128 + ch0 + (n&63)
  for (int idx = t; idx < 192 * (BK / 4); idx += 256) {
    int n = idx % 192;
    int k0 = (idx / 192) * 4;
    int col = ((n >> 6) << 7) + ch0 + (n & 63);
    float a0, a1, a2, a3;
    if (k0 < 128) {
      a0 = W_iou[(k0 + 0) * 384 + col]; a1 = W_iou[(k0 + 1) * 384 + col];
      a2 = W_iou[(k0 + 2) * 384 + col]; a3 = W_iou[(k0 + 3) * 384 + col];
    } else {
      int kk = k0 - 128;
      a0 = U_iou[(kk + 0) * 384 + col]; a1 = U_iou[(kk + 1) * 384 + col];
      a2 = U_iou[(kk + 2) * 384 + col]; a3 = U_iou[(kk + 3) * 384 + col];
    }
    *reinterpret_cast<uint2*>(Bs + swz(n, k0 * 2, RB)) = pack4(a0, a1, a2, a3);
  }
  __syncthreads();

  const int lane = t & 63, wid = t >> 6;
  const int l15 = lane & 15, l4 = lane >> 4;

  f32x4 acc[MF][12] = {};
  #pragma unroll
  for (int ks = 0; ks < BK / 32; ks++) {
    bf16x8 a[MF], b[12];
    #pragma unroll
    for (int m = 0; m < MF; m++)
      a[m] = *reinterpret_cast<const bf16x8*>(As + swz(wid * (BM / 4) + m * 16 + l15, (ks * 32 + l4 * 8) * 2, RB));
    #pragma unroll
    for (int n = 0; n < 12; n++)
      b[n] = *reinterpret_cast<const bf16x8*>(Bs + swz(n * 16 + l15, (ks * 32 + l4 * 8) * 2, RB));
    #pragma unroll
    for (int m = 0; m < MF; m++)
      #pragma unroll
      for (int n = 0; n < 12; n++)
        acc[m][n] = __builtin_amdgcn_mfma_f32_16x16x32_bf16(a[m], b[n], acc[m][n], 0, 0, 0);
  }

  // epilogue: col-frags 0-3 = i, 4-7 = o, 8-11 = u (same ch)
  #pragma unroll
  for (int m = 0; m < MF; m++) {
    int prow = pstart + p0 + wid * (BM / 4) + m * 16 + l4 * 4;
    #pragma unroll
    for (int nf = 0; nf < 4; nf++) {
      int ch = ch0 + nf * 16 + l15;
      float bi = b_iou[ch], bo = b_iou[H + ch], bu = b_iou[2 * H + ch];
      #pragma unroll
      for (int r = 0; r < 4; r++) {
        size_t o = (size_t)(prow + r) * H + ch;
        float gi = acc[m][nf][r] + bi;
        float go = acc[m][nf + 4][r] + bo;
        float gu = acc[m][nf + 8][r] + bu;
        float cs = LEAF ? 0.0f : c_glob[o];     // csum staged by fgate_kernel
        float c = fsig(gi) * ftanh(gu) + cs;
        float h = fsig(go) * ftanh(c);
        h_glob[o] = h;
        c_glob[o] = c;
      }
    }
  }
}

// ============ f32 VALU kernel for tiny top levels (0..4), 4 nodes/block ============
#define SNR 4
#define SRP 2

__global__ __launch_bounds__(256)
void small_kernel(const float* __restrict__ x,
                  const float* __restrict__ W_iou, const float* __restrict__ b_iou,
                  const float* __restrict__ U_iou, const float* __restrict__ W_f,
                  const float* __restrict__ U_f, const float* __restrict__ b_f,
                  float* __restrict__ h_out, float* __restrict__ c_out,
                  int lvl_start, int child_start, int n_lvl)
{
  __shared__ float xs[SNR][H];
  __shared__ float hs[SNR * BR][H];
  __shared__ float ht[SNR][H];
  const int t = threadIdx.x;
  const int node0 = blockIdx.x * SNR;
  const int nrows = min(SNR, n_lvl - node0);

  {
    const f32x4* xgv = reinterpret_cast<const f32x4*>(x + (size_t)(lvl_start + node0) * H);
    f32x4* xsv = reinterpret_cast<f32x4*>(&xs[0][0]);
    int total = nrows * (H / 4);
    for (int i = t; i < total; i += 256) xsv[i] = xgv[i];
  }
  {
    const f32x4* hgv = reinterpret_cast<const f32x4*>(h_out + (size_t)(child_start + node0 * BR) * H);
    f32x4* hsv = reinterpret_cast<f32x4*>(&hs[0][0]);
    int total = nrows * BR * (H / 4);
    for (int i = t; i < total; i += 256) hsv[i] = hgv[i];
  }
  __syncthreads();

  const int ch = t & (H - 1);
  const int g = t >> 7;

  float fx[SRP], ai[SRP], ao[SRP], au[SRP];
  {
    float bi = b_iou[ch], bo = b_iou[ch + H], bu = b_iou[ch + 2 * H], bf = b_f[ch];
    #pragma unroll
    for (int r = 0; r < SRP; r++) { fx[r] = bf; ai[r] = bi; ao[r] = bo; au[r] = bu; }
  }
  {
    const float* wfp = W_f + ch;
    const float* wip = W_iou + ch;
    #pragma unroll 4
    for (int k = 0; k < H; k++) {
      float wf = wfp[k * H];
      float w0 = wip[k * 384], w1 = wip[k * 384 + H], w2 = wip[k * 384 + 2 * H];
      #pragma unroll
      for (int r = 0; r < SRP; r++) {
        float xk = xs[g * SRP + r][k];
        fx[r] = fmaf(xk, wf, fx[r]);
        ai[r] = fmaf(xk, w0, ai[r]);
        ao[r] = fmaf(xk, w1, ao[r]);
        au[r] = fmaf(xk, w2, au[r]);
      }
    }
  }
  #pragma unroll
  for (int r = 0; r < SRP; r++) {
    int row = g * SRP + r;
    float s = hs[row * BR + 0][ch] + hs[row * BR + 1][ch]
            + hs[row * BR + 2][ch] + hs[row * BR + 3][ch];
    ht[row][ch] = s;
  }
  __syncthreads();

  float z[BR][SRP];
  #pragma unroll
  for (int kc = 0; kc < BR; kc++)
    #pragma unroll
    for (int r = 0; r < SRP; r++) z[kc][r] = fx[r];
  {
    const float* ufp = U_f + ch;
    #pragma unroll 4
    for (int m = 0; m < H; m++) {
      float uf = ufp[m * H];
      #pragma unroll
      for (int kc = 0; kc < BR; kc++)
        #pragma unroll
        for (int r = 0; r < SRP; r++)
          z[kc][r] = fmaf(hs[(g * SRP + r) * BR + kc][m], uf, z[kc][r]);
    }
  }
  float csum[SRP];
  #pragma unroll
  for (int r = 0; r < SRP; r++) csum[r] = 0.0f;
  #pragma unroll
  for (int kc = 0; kc < BR; kc++) {
    #pragma unroll
    for (int r = 0; r < SRP; r++) {
      size_t childnode = (size_t)child_start + (size_t)(node0 + g * SRP + r) * BR + kc;
      float f = fsig(z[kc][r]);
      csum[r] = fmaf(f, c_out[childnode * H + ch], csum[r]);
    }
  }
  {
    const float* uip = U_iou + ch;
    #pragma unroll 4
    for (int m = 0; m < H; m++) {
      float w0 = uip[m * 384], w1 = uip[m * 384 + H], w2 = uip[m * 384 + 2 * H];
      #pragma unroll
      for (int r = 0; r < SRP; r++) {
        float hm = ht[g * SRP + r][m];
        ai[r] = fmaf(hm, w0, ai[r]);
        ao[r] = fmaf(hm, w1, ao[r]);
        au[r] = fmaf(hm, w2, au[r]);
      }
    }
  }
  #pragma unroll
  for (int r = 0; r < SRP; r++) {
    int row = g * SRP + r;
    if (row < nrows) {
      float c = fsig(ai[r]) * ftanh(au[r]) + csum[r];
      float h = fsig(ao[r]) * ftanh(c);
      size_t node = (size_t)(lvl_start + node0 + row);
      h_out[node * H + ch] = h;
      c_out[node * H + ch] = c;
    }
  }
}

extern "C" void kernel_launch(void* const* d_in, const int* in_sizes, int n_in,
                              void* d_out, int out_size, void* d_ws, size_t ws_size,
                              hipStream_t stream)
{
  const float* x     = (const float*)d_in[0];
  const float* W_iou = (const float*)d_in[1];
  const float* U_iou = (const float*)d_in[2];
  const float* b_iou = (const float*)d_in[3];
  const float* W_f   = (const float*)d_in[4];
  const float* U_f   = (const float*)d_in[5];
  const float* b_f   = (const float*)d_in[6];
  const int N = 349525;

  float* h_out = (float*)d_out;
  float* c_out = h_out + (size_t)N * H;

  int off[11];
  off[0] = 0;
  for (int l = 1; l <= 10; l++) off[l] = off[l - 1] * 4 + 1;

  // leaves (level 9): 262144 nodes, MFMA
  iou_kernel<128, 128, true><<<dim3(2048, 2), 256, 0, stream>>>(
      x, W_iou, U_iou, b_iou, h_out, c_out, off[9], 0);

  // levels 8..5: MFMA (F then IOU)
  for (int l = 8; l >= 5; l--) {
    int n = off[l + 1] - off[l];
    fgate_kernel<<<n / 32, 256, 0, stream>>>(x, U_f, W_f, b_f, h_out, c_out, off[l], off[l + 1]);
    iou_kernel<64, 256, false><<<dim3(n / 64, 2), 256, 0, stream>>>(
        x, W_iou, U_iou, b_iou, h_out, c_out, off[l], off[l + 1]);
  }

  // levels 4..0: f32 VALU (precision-critical top of tree, tiny)
  for (int l = 4; l >= 0; l--) {
    int s = off[l], e = off[l + 1];
    int n = e - s;
    int grid = (n + SNR - 1) / SNR;
    small_kernel<<<grid, 256, 0, stream>>>(x, W_iou, b_iou, U_iou, W_f, U_f, b_f,
                                           h_out, c_out, s, e, n);
  }
}

// Round 3
// 663.937 us; speedup vs baseline: 1.8793x; 1.7806x over previous
//
#include <hip/hip_runtime.h>

#define H 128
#define BR 4

typedef __bf16 bf16x8 __attribute__((ext_vector_type(8)));
typedef float f32x4 __attribute__((ext_vector_type(4)));

__device__ __forceinline__ float fsig(float x) { return 1.0f / (1.0f + __expf(-x)); }
__device__ __forceinline__ float ftanh(float x) {
  float ax = fabsf(x), e = __expf(-2.0f * ax);
  float t = (1.0f - e) / (1.0f + e);
  return x < 0.0f ? -t : t;
}
__device__ __forceinline__ unsigned short f2bf(float f) {
  union { float f; unsigned u; } v; v.f = f;
  unsigned r = v.u + 0x7FFF + ((v.u >> 16) & 1);   // RNE
  return (unsigned short)(r >> 16);
}
__device__ __forceinline__ uint2 pack4(float a, float b, float c, float d) {
  uint2 r;
  r.x = (unsigned)f2bf(a) | ((unsigned)f2bf(b) << 16);
  r.y = (unsigned)f2bf(c) | ((unsigned)f2bf(d) << 16);
  return r;
}
__device__ __forceinline__ unsigned swz(unsigned row, unsigned colByte, unsigned rowBytes) {
  return (row * rowBytes + colByte) ^ ((row & 7) << 4);
}

// ws layout: [0, 64KB) fgate_fmt: 8 frags x 8 ks x 64 lane x 8 bf16
//            [64KB, 256KB) iou_fmt: 24 frags x 8 ks x 64 lane x 8 bf16
// frag element offset = frag*4096 + ks*512 + lane*8

// ============ prep: format weights into MFMA B-fragment order ============
__global__ __launch_bounds__(256)
void prep_weights(const float* __restrict__ W_iou, const float* __restrict__ U_iou,
                  const float* __restrict__ W_f, const float* __restrict__ U_f,
                  uint4* __restrict__ ws)
{
  int item = blockIdx.x * 256 + threadIdx.x;   // [0, 16384)
  unsigned short e[8];
  if (item < 4096) {
    // fgate: B = [U_f ; W_f], row n = ch
    int fj = item >> 9, rem = item & 511;
    int ks = rem >> 6, lane = rem & 63;
    int n = fj * 16 + (lane & 15);
    int kb = ks * 32 + (lane >> 4) * 8;
    #pragma unroll
    for (int j = 0; j < 8; j++) {
      int k = kb + j;
      float v = (k < 128) ? U_f[k * H + n] : W_f[(k - 128) * H + n];
      e[j] = f2bf(v);
    }
  } else {
    // iou: B = [W_iou ; U_iou], gate-gathered per ch-half
    int idx2 = item - 4096;
    int fj = idx2 >> 9, rem = idx2 & 511;
    int y = fj / 12, nf = fj % 12;
    int ks = rem >> 6, lane = rem & 63;
    int n = nf * 16 + (lane & 15);
    int col = ((n >> 6) << 7) + y * 64 + (n & 63);
    int kb = ks * 32 + (lane >> 4) * 8;
    #pragma unroll
    for (int j = 0; j < 8; j++) {
      int k = kb + j;
      float v = (k < 128) ? W_iou[k * 384 + col] : U_iou[(k - 128) * 384 + col];
      e[j] = f2bf(v);
    }
  }
  uint4 w;
  w.x = e[0] | (e[1] << 16); w.y = e[2] | (e[3] << 16);
  w.z = e[4] | (e[5] << 16); w.w = e[6] | (e[7] << 16);
  ws[item] = w;
}

// ============ leaf: h,c = apply(x@W_iou + b, 0), M=128/block, y = ch-half ============
__global__ __launch_bounds__(256)
void leaf2(const float* __restrict__ x, const __bf16* __restrict__ iou_fmt,
           const float* __restrict__ b_iou,
           float* __restrict__ h_glob, float* __restrict__ c_glob, int leaf_start)
{
  __shared__ __align__(16) char As[128 * 256];   // [128][128] bf16, swizzled
  const int t = threadIdx.x;
  const int bid = blockIdx.x, y = blockIdx.y;
  const int m0 = leaf_start + bid * 128;

  for (int i = 0; i < 16; i++) {
    int idx = t + i * 256;
    int r = idx >> 5, k0 = (idx & 31) << 2;
    f32x4 v = *reinterpret_cast<const f32x4*>(&x[(size_t)(m0 + r) * H + k0]);
    *reinterpret_cast<uint2*>(As + swz(r, k0 * 2, 256)) = pack4(v.x, v.y, v.z, v.w);
  }
  __syncthreads();

  const int lane = t & 63, wid = t >> 6;
  const int l15 = lane & 15, l4 = lane >> 4;

  f32x4 acc[2][12] = {};
  #pragma unroll
  for (int ks = 0; ks < 4; ks++) {
    bf16x8 a[2], b[12];
    #pragma unroll
    for (int m = 0; m < 2; m++)
      a[m] = *reinterpret_cast<const bf16x8*>(As + swz(wid * 32 + m * 16 + l15, (ks * 32 + l4 * 8) * 2, 256));
    #pragma unroll
    for (int n = 0; n < 12; n++)
      b[n] = *reinterpret_cast<const bf16x8*>(iou_fmt + (y * 12 + n) * 4096 + ks * 512 + lane * 8);
    #pragma unroll
    for (int m = 0; m < 2; m++)
      #pragma unroll
      for (int n = 0; n < 12; n++)
        acc[m][n] = __builtin_amdgcn_mfma_f32_16x16x32_bf16(a[m], b[n], acc[m][n], 0, 0, 0);
  }

  #pragma unroll
  for (int m = 0; m < 2; m++) {
    int prow = m0 + wid * 32 + m * 16 + l4 * 4;
    #pragma unroll
    for (int nf = 0; nf < 4; nf++) {
      int ch = y * 64 + nf * 16 + l15;
      float bi = b_iou[ch], bo = b_iou[H + ch], bu = b_iou[2 * H + ch];
      #pragma unroll
      for (int r = 0; r < 4; r++) {
        size_t o = (size_t)(prow + r) * H + ch;
        float c = fsig(acc[m][nf][r] + bi) * ftanh(acc[m][nf + 8][r] + bu);
        float h = fsig(acc[m][nf + 4][r] + bo) * ftanh(c);
        h_glob[o] = h;
        c_glob[o] = c;
      }
    }
  }
}

// ============ fgate: f = sig([h_c|x_p]@[U_f;W_f] + b_f); csum -> c[parent] ============
__global__ __launch_bounds__(256)
void fgate2(const float* __restrict__ x, const __bf16* __restrict__ f_fmt,
            const float* __restrict__ b_f,
            const float* __restrict__ h_glob, float* __restrict__ c_glob,
            int pstart, int cstart)
{
  __shared__ __align__(16) char As[128 * 512];   // [128 children][K=256] bf16
  const int t = threadIdx.x;
  const int bid = blockIdx.x;
  const int c0 = bid * 128;

  for (int i = 0; i < 32; i++) {
    int idx = t + i * 256;
    int r = idx >> 6, k0 = (idx & 63) << 2;
    f32x4 v;
    if (k0 < 128) {
      v = *reinterpret_cast<const f32x4*>(&h_glob[(size_t)(cstart + c0 + r) * H + k0]);
    } else {
      int p = pstart + ((c0 + r) >> 2);
      v = *reinterpret_cast<const f32x4*>(&x[(size_t)p * H + (k0 - 128)]);
    }
    *reinterpret_cast<uint2*>(As + swz(r, k0 * 2, 512)) = pack4(v.x, v.y, v.z, v.w);
  }
  __syncthreads();

  const int lane = t & 63, wid = t >> 6;
  const int l15 = lane & 15, l4 = lane >> 4;

  f32x4 acc[2][8] = {};
  #pragma unroll
  for (int ks = 0; ks < 8; ks++) {
    bf16x8 a[2], b[8];
    #pragma unroll
    for (int m = 0; m < 2; m++)
      a[m] = *reinterpret_cast<const bf16x8*>(As + swz(wid * 32 + m * 16 + l15, (ks * 32 + l4 * 8) * 2, 512));
    #pragma unroll
    for (int n = 0; n < 8; n++)
      b[n] = *reinterpret_cast<const bf16x8*>(f_fmt + n * 4096 + ks * 512 + lane * 8);
    #pragma unroll
    for (int m = 0; m < 2; m++)
      #pragma unroll
      for (int n = 0; n < 8; n++)
        acc[m][n] = __builtin_amdgcn_mfma_f32_16x16x32_bf16(a[m], b[n], acc[m][n], 0, 0, 0);
  }

  #pragma unroll
  for (int m = 0; m < 2; m++) {
    int rbase = wid * 32 + m * 16 + l4 * 4;        // multiple of 4
    int p = pstart + bid * 32 + (rbase >> 2);
    #pragma unroll
    for (int n = 0; n < 8; n++) {
      int ch = n * 16 + l15;
      float bf = b_f[ch];
      float cs = 0.0f;
      #pragma unroll
      for (int r = 0; r < 4; r++) {
        float f = fsig(acc[m][n][r] + bf);
        float cc = c_glob[(size_t)(cstart + c0 + rbase + r) * H + ch];
        cs = fmaf(f, cc, cs);
      }
      c_glob[(size_t)p * H + ch] = cs;   // staged; iou2 finalizes
    }
  }
}

// ============ iou: [x|h_tilda]@[W_iou;U_iou] + csum -> h,c ============
__global__ __launch_bounds__(256)
void iou2(const float* __restrict__ x, const __bf16* __restrict__ iou_fmt,
          const float* __restrict__ b_iou,
          float* __restrict__ h_glob, float* __restrict__ c_glob,
          int pstart, int cstart)
{
  __shared__ __align__(16) char As[64 * 512];    // [64 parents][K=256] bf16
  const int t = threadIdx.x;
  const int bid = blockIdx.x, y = blockIdx.y;
  const int p0 = bid * 64;

  for (int i = 0; i < 16; i++) {
    int idx = t + i * 256;
    int r = idx >> 6, k0 = (idx & 63) << 2;
    uint2 w;
    if (k0 < 128) {
      f32x4 v = *reinterpret_cast<const f32x4*>(&x[(size_t)(pstart + p0 + r) * H + k0]);
      w = pack4(v.x, v.y, v.z, v.w);
    } else {
      int cbase = cstart + (p0 + r) * 4;
      f32x4 s = {};
      #pragma unroll
      for (int j = 0; j < 4; j++) {
        f32x4 v = *reinterpret_cast<const f32x4*>(&h_glob[(size_t)(cbase + j) * H + (k0 - 128)]);
        s.x += v.x; s.y += v.y; s.z += v.z; s.w += v.w;
      }
      w = pack4(s.x, s.y, s.z, s.w);
    }
    *reinterpret_cast<uint2*>(As + swz(r, k0 * 2, 512)) = w;
  }
  __syncthreads();

  const int lane = t & 63, wid = t >> 6;
  const int l15 = lane & 15, l4 = lane >> 4;

  f32x4 acc[12] = {};
  #pragma unroll
  for (int ks = 0; ks < 8; ks++) {
    bf16x8 a, b[12];
    a = *reinterpret_cast<const bf16x8*>(As + swz(wid * 16 + l15, (ks * 32 + l4 * 8) * 2, 512));
    #pragma unroll
    for (int n = 0; n < 12; n++)
      b[n] = *reinterpret_cast<const bf16x8*>(iou_fmt + (y * 12 + n) * 4096 + ks * 512 + lane * 8);
    #pragma unroll
    for (int n = 0; n < 12; n++)
      acc[n] = __builtin_amdgcn_mfma_f32_16x16x32_bf16(a, b[n], acc[n], 0, 0, 0);
  }

  {
    int prow = pstart + p0 + wid * 16 + l4 * 4;
    #pragma unroll
    for (int nf = 0; nf < 4; nf++) {
      int ch = y * 64 + nf * 16 + l15;
      float bi = b_iou[ch], bo = b_iou[H + ch], bu = b_iou[2 * H + ch];
      #pragma unroll
      for (int r = 0; r < 4; r++) {
        size_t o = (size_t)(prow + r) * H + ch;
        float gi = acc[nf][r] + bi;
        float go = acc[nf + 4][r] + bo;
        float gu = acc[nf + 8][r] + bu;
        float cs = c_glob[o];                      // csum staged by fgate2
        float c = fsig(gi) * ftanh(gu) + cs;
        float h = fsig(go) * ftanh(c);
        h_glob[o] = h;
        c_glob[o] = c;
      }
    }
  }
}

// ============ f32 VALU kernel for tiny top levels (0..4) ============
#define SNR 4
#define SRP 2

__global__ __launch_bounds__(256)
void small_kernel(const float* __restrict__ x,
                  const float* __restrict__ W_iou, const float* __restrict__ b_iou,
                  const float* __restrict__ U_iou, const float* __restrict__ W_f,
                  const float* __restrict__ U_f, const float* __restrict__ b_f,
                  float* __restrict__ h_out, float* __restrict__ c_out,
                  int lvl_start, int child_start, int n_lvl)
{
  __shared__ float xs[SNR][H];
  __shared__ float hs[SNR * BR][H];
  __shared__ float ht[SNR][H];
  const int t = threadIdx.x;
  const int node0 = blockIdx.x * SNR;
  const int nrows = min(SNR, n_lvl - node0);

  {
    const f32x4* xgv = reinterpret_cast<const f32x4*>(x + (size_t)(lvl_start + node0) * H);
    f32x4* xsv = reinterpret_cast<f32x4*>(&xs[0][0]);
    int total = nrows * (H / 4);
    for (int i = t; i < total; i += 256) xsv[i] = xgv[i];
  }
  {
    const f32x4* hgv = reinterpret_cast<const f32x4*>(h_out + (size_t)(child_start + node0 * BR) * H);
    f32x4* hsv = reinterpret_cast<f32x4*>(&hs[0][0]);
    int total = nrows * BR * (H / 4);
    for (int i = t; i < total; i += 256) hsv[i] = hgv[i];
  }
  __syncthreads();

  const int ch = t & (H - 1);
  const int g = t >> 7;

  float fx[SRP], ai[SRP], ao[SRP], au[SRP];
  {
    float bi = b_iou[ch], bo = b_iou[ch + H], bu = b_iou[ch + 2 * H], bf = b_f[ch];
    #pragma unroll
    for (int r = 0; r < SRP; r++) { fx[r] = bf; ai[r] = bi; ao[r] = bo; au[r] = bu; }
  }
  {
    const float* wfp = W_f + ch;
    const float* wip = W_iou + ch;
    #pragma unroll 4
    for (int k = 0; k < H; k++) {
      float wf = wfp[k * H];
      float w0 = wip[k * 384], w1 = wip[k * 384 + H], w2 = wip[k * 384 + 2 * H];
      #pragma unroll
      for (int r = 0; r < SRP; r++) {
        float xk = xs[g * SRP + r][k];
        fx[r] = fmaf(xk, wf, fx[r]);
        ai[r] = fmaf(xk, w0, ai[r]);
        ao[r] = fmaf(xk, w1, ao[r]);
        au[r] = fmaf(xk, w2, au[r]);
      }
    }
  }
  #pragma unroll
  for (int r = 0; r < SRP; r++) {
    int row = g * SRP + r;
    float s = hs[row * BR + 0][ch] + hs[row * BR + 1][ch]
            + hs[row * BR + 2][ch] + hs[row * BR + 3][ch];
    ht[row][ch] = s;
  }
  __syncthreads();

  float z[BR][SRP];
  #pragma unroll
  for (int kc = 0; kc < BR; kc++)
    #pragma unroll
    for (int r = 0; r < SRP; r++) z[kc][r] = fx[r];
  {
    const float* ufp = U_f + ch;
    #pragma unroll 4
    for (int m = 0; m < H; m++) {
      float uf = ufp[m * H];
      #pragma unroll
      for (int kc = 0; kc < BR; kc++)
        #pragma unroll
        for (int r = 0; r < SRP; r++)
          z[kc][r] = fmaf(hs[(g * SRP + r) * BR + kc][m], uf, z[kc][r]);
    }
  }
  float csum[SRP];
  #pragma unroll
  for (int r = 0; r < SRP; r++) csum[r] = 0.0f;
  #pragma unroll
  for (int kc = 0; kc < BR; kc++) {
    #pragma unroll
    for (int r = 0; r < SRP; r++) {
      size_t childnode = (size_t)child_start + (size_t)(node0 + g * SRP + r) * BR + kc;
      float f = fsig(z[kc][r]);
      csum[r] = fmaf(f, c_out[childnode * H + ch], csum[r]);
    }
  }
  {
    const float* uip = U_iou + ch;
    #pragma unroll 4
    for (int m = 0; m < H; m++) {
      float w0 = uip[m * 384], w1 = uip[m * 384 + H], w2 = uip[m * 384 + 2 * H];
      #pragma unroll
      for (int r = 0; r < SRP; r++) {
        float hm = ht[g * SRP + r][m];
        ai[r] = fmaf(hm, w0, ai[r]);
        ao[r] = fmaf(hm, w1, ao[r]);
        au[r] = fmaf(hm, w2, au[r]);
      }
    }
  }
  #pragma unroll
  for (int r = 0; r < SRP; r++) {
    int row = g * SRP + r;
    if (row < nrows) {
      float c = fsig(ai[r]) * ftanh(au[r]) + csum[r];
      float h = fsig(ao[r]) * ftanh(c);
      size_t node = (size_t)(lvl_start + node0 + row);
      h_out[node * H + ch] = h;
      c_out[node * H + ch] = c;
    }
  }
}

extern "C" void kernel_launch(void* const* d_in, const int* in_sizes, int n_in,
                              void* d_out, int out_size, void* d_ws, size_t ws_size,
                              hipStream_t stream)
{
  const float* x     = (const float*)d_in[0];
  const float* W_iou = (const float*)d_in[1];
  const float* U_iou = (const float*)d_in[2];
  const float* b_iou = (const float*)d_in[3];
  const float* W_f   = (const float*)d_in[4];
  const float* U_f   = (const float*)d_in[5];
  const float* b_f   = (const float*)d_in[6];
  const int N = 349525;

  float* h_out = (float*)d_out;
  float* c_out = h_out + (size_t)N * H;

  const __bf16* f_fmt   = (const __bf16*)d_ws;            // 64 KB
  const __bf16* iou_fmt = (const __bf16*)d_ws + 32768;    // 192 KB

  int off[11];
  off[0] = 0;
  for (int l = 1; l <= 10; l++) off[l] = off[l - 1] * 4 + 1;

  prep_weights<<<64, 256, 0, stream>>>(W_iou, U_iou, W_f, U_f, (uint4*)d_ws);

  // leaves (level 9)
  leaf2<<<dim3(2048, 2), 256, 0, stream>>>(x, iou_fmt, b_iou, h_out, c_out, off[9]);

  // levels 8..5: MFMA
  for (int l = 8; l >= 5; l--) {
    int n = off[l + 1] - off[l];
    fgate2<<<n / 32, 256, 0, stream>>>(x, f_fmt, b_f, h_out, c_out, off[l], off[l + 1]);
    iou2<<<dim3(n / 64, 2), 256, 0, stream>>>(x, iou_fmt, b_iou, h_out, c_out, off[l], off[l + 1]);
  }

  // levels 4..0: f32 VALU
  for (int l = 4; l >= 0; l--) {
    int s = off[l], e = off[l + 1];
    int n = e - s;
    int grid = (n + SNR - 1) / SNR;
    small_kernel<<<grid, 256, 0, stream>>>(x, W_iou, b_iou, U_iou, W_f, U_f, b_f,
                                           h_out, c_out, s, e, n);
  }
}

// Round 4
// 409.229 us; speedup vs baseline: 3.0490x; 1.6224x over previous
//
#include <hip/hip_runtime.h>

#define H 128

typedef __bf16 bf16x8 __attribute__((ext_vector_type(8)));
typedef float f32x4 __attribute__((ext_vector_type(4)));

__device__ __forceinline__ float fsig(float x) { return 1.0f / (1.0f + __expf(-x)); }
__device__ __forceinline__ float ftanh(float x) {
  float ax = fabsf(x), e = __expf(-2.0f * ax);
  float t = (1.0f - e) / (1.0f + e);
  return x < 0.0f ? -t : t;
}
__device__ __forceinline__ uint2 pack4(float a, float b, float c, float d) {
  union { __bf16 h[4]; uint2 u; } r;
  r.h[0] = (__bf16)a; r.h[1] = (__bf16)b; r.h[2] = (__bf16)c; r.h[3] = (__bf16)d;
  return r.u;
}
__device__ __forceinline__ unsigned swz(unsigned row, unsigned colByte, unsigned rowBytes) {
  return (row * rowBytes + colByte) ^ ((row & 7) << 4);
}

// ws fragment layouts (uint4 = one lane's 8 bf16):
//   uf_fmt : frags 0..7   (U_f,  K=128, ks 0..3)   uint4[0..2048)
//   wf_fmt : frags 0..7   (W_f,  K=128, ks 0..3)   uint4[2048..4096)
//   iou_fmt: frags 0..23  ([W_iou;U_iou], K=256, ks 0..7) uint4[4096..16384)
//   iou frag nf covers gate nf>>3, cols (nf>>3)*128 + (nf&7)*16 + (lane&15)
__global__ __launch_bounds__(256)
void prep_weights(const float* __restrict__ W_iou, const float* __restrict__ U_iou,
                  const float* __restrict__ W_f, const float* __restrict__ U_f,
                  uint4* __restrict__ ws)
{
  int item = blockIdx.x * 256 + threadIdx.x;   // [0, 16384)
  float v[8];
  if (item < 2048) {
    int fj = item >> 8, rem = item & 255, ks = rem >> 6, lane = rem & 63;
    int n = fj * 16 + (lane & 15), kb = ks * 32 + (lane >> 4) * 8;
    #pragma unroll
    for (int j = 0; j < 8; j++) v[j] = U_f[(kb + j) * H + n];
  } else if (item < 4096) {
    int i2 = item - 2048;
    int fj = i2 >> 8, rem = i2 & 255, ks = rem >> 6, lane = rem & 63;
    int n = fj * 16 + (lane & 15), kb = ks * 32 + (lane >> 4) * 8;
    #pragma unroll
    for (int j = 0; j < 8; j++) v[j] = W_f[(kb + j) * H + n];
  } else {
    int i2 = item - 4096;
    int fj = i2 >> 9, rem = i2 & 511, ks = rem >> 6, lane = rem & 63;
    int col = (fj >> 3) * 128 + (fj & 7) * 16 + (lane & 15);
    int kb = ks * 32 + (lane >> 4) * 8;
    #pragma unroll
    for (int j = 0; j < 8; j++) {
      int k = kb + j;
      v[j] = (k < 128) ? W_iou[k * 384 + col] : U_iou[(k - 128) * 384 + col];
    }
  }
  union { __bf16 h[8]; uint4 u; } r;
  #pragma unroll
  for (int j = 0; j < 8; j++) r.h[j] = (__bf16)v[j];
  ws[item] = r.u;
}

// ============ leaf: h,c = apply(x@W_iou + b, 0); M=64/block, waves split N=384 ============
__global__ __launch_bounds__(256)
void leaf3(const float* __restrict__ x, const __bf16* __restrict__ iou_fmt,
           const float* __restrict__ b_iou,
           float* __restrict__ h_glob, float* __restrict__ c_glob, int leaf_start)
{
  __shared__ __align__(16) char As[64 * 256];   // [64][128] bf16 swizzled
  const int t = threadIdx.x;
  const int m0 = leaf_start + blockIdx.x * 64;

  #pragma unroll
  for (int i = 0; i < 8; i++) {
    int idx = t + i * 256;
    int r = idx >> 5, k0 = (idx & 31) << 2;
    f32x4 v = *reinterpret_cast<const f32x4*>(&x[(size_t)(m0 + r) * H + k0]);
    *reinterpret_cast<uint2*>(As + swz(r, k0 * 2, 256)) = pack4(v.x, v.y, v.z, v.w);
  }
  __syncthreads();

  const int lane = t & 63, w = t >> 6;
  const int l15 = lane & 15, l4 = lane >> 4;

  f32x4 acc[4][3][2] = {};
  #pragma unroll
  for (int ks = 0; ks < 4; ks++) {
    bf16x8 a[4], b[3][2];
    #pragma unroll
    for (int m = 0; m < 4; m++)
      a[m] = *reinterpret_cast<const bf16x8*>(As + swz(m * 16 + l15, (ks * 32 + l4 * 8) * 2, 256));
    #pragma unroll
    for (int g = 0; g < 3; g++)
      #pragma unroll
      for (int j = 0; j < 2; j++) {
        int nf = g * 8 + 2 * w + j;
        b[g][j] = *reinterpret_cast<const bf16x8*>(iou_fmt + ((size_t)(nf * 8 + ks) * 64 + lane) * 8);
      }
    #pragma unroll
    for (int m = 0; m < 4; m++)
      #pragma unroll
      for (int g = 0; g < 3; g++)
        #pragma unroll
        for (int j = 0; j < 2; j++)
          acc[m][g][j] = __builtin_amdgcn_mfma_f32_16x16x32_bf16(a[m], b[g][j], acc[m][g][j], 0, 0, 0);
  }

  #pragma unroll
  for (int j = 0; j < 2; j++) {
    int ch = (2 * w + j) * 16 + l15;
    float bi = b_iou[ch], bo = b_iou[H + ch], bu = b_iou[2 * H + ch];
    #pragma unroll
    for (int m = 0; m < 4; m++) {
      int rowb = m * 16 + l4 * 4;
      #pragma unroll
      for (int r = 0; r < 4; r++) {
        size_t o = (size_t)(m0 + rowb + r) * H + ch;
        float c = fsig(acc[m][0][j][r] + bi) * ftanh(acc[m][2][j][r] + bu);
        float h = fsig(acc[m][1][j][r] + bo) * ftanh(c);
        h_glob[o] = h;
        c_glob[o] = c;
      }
    }
  }
}

// ============ fused level kernel: 32 parents / 128 children per block ============
__global__ __launch_bounds__(256)
void fused_level(const float* __restrict__ x, const __bf16* __restrict__ uf_fmt,
                 const __bf16* __restrict__ wf_fmt, const __bf16* __restrict__ iou_fmt,
                 const float* __restrict__ b_iou, const float* __restrict__ b_f,
                 float* __restrict__ h_glob, float* __restrict__ c_glob,
                 int pstart, int cstart)
{
  __shared__ __align__(16) char CH[128 * 256];   // children h bf16 [128][128] swz
  __shared__ __align__(16) char XH[32 * 512];    // [x | h_tilda] bf16 [32][256] swz
  __shared__ float SFX[32][128];                 // x @ W_f
  __shared__ float CSUM[32][128];                // sum_k f*c_child
  const int t = threadIdx.x;
  const int p0 = blockIdx.x * 32;
  const int c0 = blockIdx.x * 128;

  // stage children h (+ h_tilda) and parent x
  #pragma unroll
  for (int i = 0; i < 4; i++) {
    int idx = t + i * 256;                       // [0,1024)
    int p = idx >> 5, k0 = (idx & 31) << 2;
    f32x4 s = {};
    #pragma unroll
    for (int j = 0; j < 4; j++) {
      f32x4 v = *reinterpret_cast<const f32x4*>(&h_glob[(size_t)(cstart + c0 + p * 4 + j) * H + k0]);
      *reinterpret_cast<uint2*>(CH + swz(p * 4 + j, k0 * 2, 256)) = pack4(v.x, v.y, v.z, v.w);
      s += v;
    }
    *reinterpret_cast<uint2*>(XH + swz(p, (128 + k0) * 2, 512)) = pack4(s.x, s.y, s.z, s.w);
  }
  #pragma unroll
  for (int i = 0; i < 4; i++) {
    int idx = t + i * 256;
    int p = idx >> 5, k0 = (idx & 31) << 2;
    f32x4 v = *reinterpret_cast<const f32x4*>(&x[(size_t)(pstart + p0 + p) * H + k0]);
    *reinterpret_cast<uint2*>(XH + swz(p, k0 * 2, 512)) = pack4(v.x, v.y, v.z, v.w);
  }
  __syncthreads();

  const int lane = t & 63, w = t >> 6;
  const int l15 = lane & 15, l4 = lane >> 4;

  // P1: SFX = x @ W_f (M=32, N=128, waves split N: 2 frags each)
  {
    f32x4 acc[2][2] = {};
    #pragma unroll
    for (int ks = 0; ks < 4; ks++) {
      bf16x8 a[2], b[2];
      #pragma unroll
      for (int m = 0; m < 2; m++)
        a[m] = *reinterpret_cast<const bf16x8*>(XH + swz(m * 16 + l15, (ks * 32 + l4 * 8) * 2, 512));
      #pragma unroll
      for (int n = 0; n < 2; n++) {
        int nf = 2 * w + n;
        b[n] = *reinterpret_cast<const bf16x8*>(wf_fmt + ((size_t)(nf * 4 + ks) * 64 + lane) * 8);
      }
      #pragma unroll
      for (int m = 0; m < 2; m++)
        #pragma unroll
        for (int n = 0; n < 2; n++)
          acc[m][n] = __builtin_amdgcn_mfma_f32_16x16x32_bf16(a[m], b[n], acc[m][n], 0, 0, 0);
    }
    #pragma unroll
    for (int m = 0; m < 2; m++)
      #pragma unroll
      for (int n = 0; n < 2; n++)
        #pragma unroll
        for (int r = 0; r < 4; r++)
          SFX[m * 16 + l4 * 4 + r][(2 * w + n) * 16 + l15] = acc[m][n][r];
  }
  __syncthreads();

  // P2: f = sig(h_child@U_f + SFX[parent] + b_f); CSUM = sum f*c_child
  {
    f32x4 acc[2][8] = {};
    #pragma unroll
    for (int ks = 0; ks < 4; ks++) {
      bf16x8 a[2], b[8];
      #pragma unroll
      for (int m = 0; m < 2; m++)
        a[m] = *reinterpret_cast<const bf16x8*>(CH + swz(w * 32 + m * 16 + l15, (ks * 32 + l4 * 8) * 2, 256));
      #pragma unroll
      for (int n = 0; n < 8; n++)
        b[n] = *reinterpret_cast<const bf16x8*>(uf_fmt + ((size_t)(n * 4 + ks) * 64 + lane) * 8);
      #pragma unroll
      for (int m = 0; m < 2; m++)
        #pragma unroll
        for (int n = 0; n < 8; n++)
          acc[m][n] = __builtin_amdgcn_mfma_f32_16x16x32_bf16(a[m], b[n], acc[m][n], 0, 0, 0);
    }
    #pragma unroll
    for (int m = 0; m < 2; m++) {
      int rbase = w * 32 + m * 16 + l4 * 4;      // child-local, multiple of 4
      int ploc = rbase >> 2;
      #pragma unroll
      for (int n = 0; n < 8; n++) {
        int ch = n * 16 + l15;
        float sfx = SFX[ploc][ch] + b_f[ch];
        float cs = 0.0f;
        #pragma unroll
        for (int r = 0; r < 4; r++) {
          float f = fsig(acc[m][n][r] + sfx);
          cs = fmaf(f, c_glob[(size_t)(cstart + c0 + rbase + r) * H + ch], cs);
        }
        CSUM[ploc][ch] = cs;
      }
    }
  }
  __syncthreads();

  // P3: iou = [x|h_tilda] @ [W_iou;U_iou]; finalize h,c
  {
    f32x4 acc[2][3][2] = {};
    #pragma unroll
    for (int ks = 0; ks < 8; ks++) {
      bf16x8 a[2], b[3][2];
      #pragma unroll
      for (int m = 0; m < 2; m++)
        a[m] = *reinterpret_cast<const bf16x8*>(XH + swz(m * 16 + l15, (ks * 32 + l4 * 8) * 2, 512));
      #pragma unroll
      for (int g = 0; g < 3; g++)
        #pragma unroll
        for (int j = 0; j < 2; j++) {
          int nf = g * 8 + 2 * w + j;
          b[g][j] = *reinterpret_cast<const bf16x8*>(iou_fmt + ((size_t)(nf * 8 + ks) * 64 + lane) * 8);
        }
      #pragma unroll
      for (int m = 0; m < 2; m++)
        #pragma unroll
        for (int g = 0; g < 3; g++)
          #pragma unroll
          for (int j = 0; j < 2; j++)
            acc[m][g][j] = __builtin_amdgcn_mfma_f32_16x16x32_bf16(a[m], b[g][j], acc[m][g][j], 0, 0, 0);
    }
    #pragma unroll
    for (int j = 0; j < 2; j++) {
      int ch = (2 * w + j) * 16 + l15;
      float bi = b_iou[ch], bo = b_iou[H + ch], bu = b_iou[2 * H + ch];
      #pragma unroll
      for (int m = 0; m < 2; m++) {
        #pragma unroll
        for (int r = 0; r < 4; r++) {
          int ploc = m * 16 + l4 * 4 + r;
          float gi = acc[m][0][j][r] + bi;
          float go = acc[m][1][j][r] + bo;
          float gu = acc[m][2][j][r] + bu;
          float cs = CSUM[ploc][ch];
          float c = fsig(gi) * ftanh(gu) + cs;
          float h = fsig(go) * ftanh(c);
          size_t o = (size_t)(pstart + p0 + ploc) * H + ch;
          h_glob[o] = h;
          c_glob[o] = c;
        }
      }
    }
  }
}

// ============ f32 VALU kernel for tiny top levels (0..4) ============
#define SNR 4
#define SRP 2
#define BR 4

__global__ __launch_bounds__(256)
void small_kernel(const float* __restrict__ x,
                  const float* __restrict__ W_iou, const float* __restrict__ b_iou,
                  const float* __restrict__ U_iou, const float* __restrict__ W_f,
                  const float* __restrict__ U_f, const float* __restrict__ b_f,
                  float* __restrict__ h_out, float* __restrict__ c_out,
                  int lvl_start, int child_start, int n_lvl)
{
  __shared__ float xs[SNR][H];
  __shared__ float hs[SNR * BR][H];
  __shared__ float ht[SNR][H];
  const int t = threadIdx.x;
  const int node0 = blockIdx.x * SNR;
  const int nrows = min(SNR, n_lvl - node0);

  {
    const f32x4* xgv = reinterpret_cast<const f32x4*>(x + (size_t)(lvl_start + node0) * H);
    f32x4* xsv = reinterpret_cast<f32x4*>(&xs[0][0]);
    int total = nrows * (H / 4);
    for (int i = t; i < total; i += 256) xsv[i] = xgv[i];
  }
  {
    const f32x4* hgv = reinterpret_cast<const f32x4*>(h_out + (size_t)(child_start + node0 * BR) * H);
    f32x4* hsv = reinterpret_cast<f32x4*>(&hs[0][0]);
    int total = nrows * BR * (H / 4);
    for (int i = t; i < total; i += 256) hsv[i] = hgv[i];
  }
  __syncthreads();

  const int ch = t & (H - 1);
  const int g = t >> 7;

  float fx[SRP], ai[SRP], ao[SRP], au[SRP];
  {
    float bi = b_iou[ch], bo = b_iou[ch + H], bu = b_iou[ch + 2 * H], bf = b_f[ch];
    #pragma unroll
    for (int r = 0; r < SRP; r++) { fx[r] = bf; ai[r] = bi; ao[r] = bo; au[r] = bu; }
  }
  {
    const float* wfp = W_f + ch;
    const float* wip = W_iou + ch;
    #pragma unroll 4
    for (int k = 0; k < H; k++) {
      float wf = wfp[k * H];
      float w0 = wip[k * 384], w1 = wip[k * 384 + H], w2 = wip[k * 384 + 2 * H];
      #pragma unroll
      for (int r = 0; r < SRP; r++) {
        float xk = xs[g * SRP + r][k];
        fx[r] = fmaf(xk, wf, fx[r]);
        ai[r] = fmaf(xk, w0, ai[r]);
        ao[r] = fmaf(xk, w1, ao[r]);
        au[r] = fmaf(xk, w2, au[r]);
      }
    }
  }
  #pragma unroll
  for (int r = 0; r < SRP; r++) {
    int row = g * SRP + r;
    float s = hs[row * BR + 0][ch] + hs[row * BR + 1][ch]
            + hs[row * BR + 2][ch] + hs[row * BR + 3][ch];
    ht[row][ch] = s;
  }
  __syncthreads();

  float z[BR][SRP];
  #pragma unroll
  for (int kc = 0; kc < BR; kc++)
    #pragma unroll
    for (int r = 0; r < SRP; r++) z[kc][r] = fx[r];
  {
    const float* ufp = U_f + ch;
    #pragma unroll 4
    for (int m = 0; m < H; m++) {
      float uf = ufp[m * H];
      #pragma unroll
      for (int kc = 0; kc < BR; kc++)
        #pragma unroll
        for (int r = 0; r < SRP; r++)
          z[kc][r] = fmaf(hs[(g * SRP + r) * BR + kc][m], uf, z[kc][r]);
    }
  }
  float csum[SRP];
  #pragma unroll
  for (int r = 0; r < SRP; r++) csum[r] = 0.0f;
  #pragma unroll
  for (int kc = 0; kc < BR; kc++) {
    #pragma unroll
    for (int r = 0; r < SRP; r++) {
      size_t childnode = (size_t)child_start + (size_t)(node0 + g * SRP + r) * BR + kc;
      float f = fsig(z[kc][r]);
      csum[r] = fmaf(f, c_out[childnode * H + ch], csum[r]);
    }
  }
  {
    const float* uip = U_iou + ch;
    #pragma unroll 4
    for (int m = 0; m < H; m++) {
      float w0 = uip[m * 384], w1 = uip[m * 384 + H], w2 = uip[m * 384 + 2 * H];
      #pragma unroll
      for (int r = 0; r < SRP; r++) {
        float hm = ht[g * SRP + r][m];
        ai[r] = fmaf(hm, w0, ai[r]);
        ao[r] = fmaf(hm, w1, ao[r]);
        au[r] = fmaf(hm, w2, au[r]);
      }
    }
  }
  #pragma unroll
  for (int r = 0; r < SRP; r++) {
    int row = g * SRP + r;
    if (row < nrows) {
      float c = fsig(ai[r]) * ftanh(au[r]) + csum[r];
      float h = fsig(ao[r]) * ftanh(c);
      size_t node = (size_t)(lvl_start + node0 + row);
      h_out[node * H + ch] = h;
      c_out[node * H + ch] = c;
    }
  }
}

extern "C" void kernel_launch(void* const* d_in, const int* in_sizes, int n_in,
                              void* d_out, int out_size, void* d_ws, size_t ws_size,
                              hipStream_t stream)
{
  const float* x     = (const float*)d_in[0];
  const float* W_iou = (const float*)d_in[1];
  const float* U_iou = (const float*)d_in[2];
  const float* b_iou = (const float*)d_in[3];
  const float* W_f   = (const float*)d_in[4];
  const float* U_f   = (const float*)d_in[5];
  const float* b_f   = (const float*)d_in[6];
  const int N = 349525;

  float* h_out = (float*)d_out;
  float* c_out = h_out + (size_t)N * H;

  const __bf16* uf_fmt  = (const __bf16*)d_ws;             // 32 KB
  const __bf16* wf_fmt  = (const __bf16*)d_ws + 16384;     // 32 KB
  const __bf16* iou_fmt = (const __bf16*)d_ws + 32768;     // 192 KB

  int off[11];
  off[0] = 0;
  for (int l = 1; l <= 10; l++) off[l] = off[l - 1] * 4 + 1;

  prep_weights<<<64, 256, 0, stream>>>(W_iou, U_iou, W_f, U_f, (uint4*)d_ws);

  // leaves (level 9): 262144 nodes
  leaf3<<<4096, 256, 0, stream>>>(x, iou_fmt, b_iou, h_out, c_out, off[9]);

  // levels 8..5: fused MFMA (parents = 4^l, all multiples of 32)
  for (int l = 8; l >= 5; l--) {
    int n_par = off[l + 1] - off[l];
    fused_level<<<n_par / 32, 256, 0, stream>>>(x, uf_fmt, wf_fmt, iou_fmt, b_iou, b_f,
                                                h_out, c_out, off[l], off[l + 1]);
  }

  // levels 4..0: f32 VALU
  for (int l = 4; l >= 0; l--) {
    int s = off[l], e = off[l + 1];
    int n = e - s;
    int grid = (n + SNR - 1) / SNR;
    small_kernel<<<grid, 256, 0, stream>>>(x, W_iou, b_iou, U_iou, W_f, U_f, b_f,
                                           h_out, c_out, s, e, n);
  }
}